// Round 3
// baseline (977.283 us; speedup 1.0000x reference)
//
#include <hip/hip_runtime.h>

#define D 64
#define NCH 8   // feature chunks
#define CW 8    // features per chunk

// ---------------- degree ----------------

__global__ void deg_init_k(unsigned int* deg, unsigned int* cursor, int n) {
    int i = blockIdx.x * blockDim.x + threadIdx.x;
    if (i < n) deg[i] = 1u;  // self-loop
    if (i == 0) *cursor = 0u;
}

__global__ void deg_count_k(const int* __restrict__ col, unsigned int* deg, int E) {
    int e = blockIdx.x * blockDim.x + threadIdx.x;
    if (e < E) atomicAdd(&deg[col[e]], 1u);
}

// ---------------- dinv + scan-free CSR segment allocation ----------------

__global__ void alloc_k(const unsigned int* __restrict__ deg, float* __restrict__ dinv,
                        unsigned int* __restrict__ cur, unsigned int* cursor, int n) {
    int i = blockIdx.x * blockDim.x + threadIdx.x;
    int lane = threadIdx.x & 63;
    unsigned int dg = (i < n) ? deg[i] : 1u;
    if (i < n) dinv[i] = rsqrtf((float)dg);  // dg >= 1 (self-loop)
    unsigned int cnt = (i < n) ? (dg - 1u) : 0u;  // in-edges only
    unsigned int v = cnt;  // inclusive wave scan
#pragma unroll
    for (int off = 1; off < 64; off <<= 1) {
        unsigned int t = (unsigned int)__shfl_up((int)v, off, 64);
        if (lane >= off) v += t;
    }
    unsigned int base = 0;
    if (lane == 63) base = atomicAdd(cursor, v);
    base = (unsigned int)__shfl((int)base, 63, 64);
    if (i < n) cur[i] = base + v - cnt;  // segment start; bucket advances to end
}

// ---------------- bucket edges into CSR (src only; weights recomputed) ----------------

__global__ void bucket_k(const int* __restrict__ row, const int* __restrict__ col,
                         unsigned int* __restrict__ cur, int* __restrict__ csr_src, int E) {
    int e = blockIdx.x * blockDim.x + threadIdx.x;
    if (e >= E) return;
    int j = row[e], i = col[e];
    unsigned int pos = atomicAdd(&cur[i], 1u);
    csr_src[pos] = j;
}

// ---------------- chunked hop: one wave per node, lanes = 8 edges x 8 features ----------
// chunk = blockIdx.x % 8 -> round-robin workgroup->XCD dispatch gives each XCD one
// 3.2 MB feature slice of h_in, which stays L2-resident across the whole hop.

__global__ __launch_bounds__(256) void hop_k(const float* __restrict__ h_in,
                                             const float* __restrict__ dinv,
                                             const unsigned int* __restrict__ deg,
                                             const unsigned int* __restrict__ cur,
                                             const int* __restrict__ csr_src,
                                             float* __restrict__ h_out, int n) {
    int chunk = blockIdx.x & (NCH - 1);
    int nb = blockIdx.x >> 3;
    int w = threadIdx.x >> 6, lane = threadIdx.x & 63;
    int i = nb * 4 + w;
    if (i >= n) return;
    int es = lane >> 3;          // edge slot 0..7
    int fo = chunk * CW + (lane & 7);  // global feature index
    float di = dinv[i];
    unsigned int end = cur[i];
    unsigned int cnt = deg[i] - 1u;
    float acc = 0.0f;
    for (unsigned int e = end - cnt + es; e < end; e += 8) {
        int j = csr_src[e];
        acc = fmaf(dinv[j] * di, h_in[(size_t)j * D + fo], acc);
    }
    // reduce over edge slots (lane stride 8): xor on lane bits 3,4,5
    acc += __shfl_xor(acc, 8, 64);
    acc += __shfl_xor(acc, 16, 64);
    acc += __shfl_xor(acc, 32, 64);
    if (es == 0) {
        acc += di * di * h_in[(size_t)i * D + fo];  // self-loop term
        h_out[(size_t)i * D + fo] = acc;
    }
}

// ---------------- linear + bias + relu (padded Wt: no bank conflicts) ----------------

__global__ __launch_bounds__(256) void linear_relu_k(const float* __restrict__ h,
                                                     const float* __restrict__ W,
                                                     const float* __restrict__ b,
                                                     float* __restrict__ out, int n) {
    __shared__ float Wt[D][D + 1];  // Wt[d][o] = W[o][d]; +1 pad -> conflict-free staging
    __shared__ float hrow[4][D];
    int tid = threadIdx.x;
    for (int k = tid; k < D * D; k += 256) Wt[k & 63][k >> 6] = W[k];
    int li = tid >> 6;
    int o  = tid & 63;
    int i  = blockIdx.x * 4 + li;
    if (i < n) hrow[li][o] = h[(size_t)i * D + o];
    __syncthreads();
    if (i >= n) return;
    float acc = b[o];
#pragma unroll
    for (int d = 0; d < D; ++d) acc = fmaf(hrow[li][d], Wt[d][o], acc);
    out[(size_t)i * D + o] = fmaxf(acc, 0.0f);
}

// ---------------- launch ----------------

extern "C" void kernel_launch(void* const* d_in, const int* in_sizes, int n_in,
                              void* d_out, int out_size, void* d_ws, size_t ws_size,
                              hipStream_t stream) {
    const float* x = (const float*)d_in[0];  // [n, 64]
    const float* W = (const float*)d_in[1];  // [64, 64]
    const float* b = (const float*)d_in[2];  // [64]
    const int*   ei = (const int*)d_in[3];   // [2, E] int32

    const int n = in_sizes[0] / D;
    const int E = in_sizes[3] / 2;
    const int* row = ei;       // sources j
    const int* col = ei + E;   // targets i
    float* out = (float*)d_out;

    // ws (~33 MB): deg | dinv | cur | cursor | csr_src | h1.  h2 lives in d_out
    // (safe: linear_relu_k blocks only read their own nodes' rows before writing them).
    char* ws = (char*)d_ws;
    unsigned int* deg     = (unsigned int*)ws;                        // n u32
    float*        dinv    = (float*)(ws + (size_t)n * 4);             // n f32
    unsigned int* cur     = (unsigned int*)(ws + (size_t)n * 8);      // n u32
    unsigned int* cursor  = (unsigned int*)(ws + (size_t)n * 12);     // 1 u32 (+pad)
    int*          csr_src = (int*)(ws + (size_t)n * 12 + 16);         // E i32
    float*        h1      = (float*)(ws + (size_t)n * 12 + 16 + (size_t)E * 4);  // n*64 f32
    float*        h2      = out;

    const int nb = (n + 255) / 256;
    const int eb = (E + 255) / 256;
    const int hb = NCH * ((n + 3) / 4);  // chunk-major: blockIdx%8 = chunk -> XCD affinity
    const int lb = (n + 3) / 4;

    deg_init_k<<<nb, 256, 0, stream>>>(deg, cursor, n);
    deg_count_k<<<eb, 256, 0, stream>>>(col, deg, E);
    alloc_k<<<nb, 256, 0, stream>>>(deg, dinv, cur, cursor, n);
    bucket_k<<<eb, 256, 0, stream>>>(row, col, cur, csr_src, E);

    hop_k<<<hb, 256, 0, stream>>>(x, dinv, deg, cur, csr_src, h1, n);
    hop_k<<<hb, 256, 0, stream>>>(h1, dinv, deg, cur, csr_src, h2, n);
    linear_relu_k<<<lb, 256, 0, stream>>>(h2, W, b, out, n);
}

// Round 4
// 471.873 us; speedup vs baseline: 2.0711x; 2.0711x over previous
//
#include <hip/hip_runtime.h>

#define D 64

// ---------------- degree ----------------

__global__ void deg_init_k(unsigned int* deg, unsigned int* cursor, int n) {
    int i = blockIdx.x * blockDim.x + threadIdx.x;
    if (i < n) deg[i] = 1u;  // self-loop
    if (i == 0) *cursor = 0u;
}

__global__ void deg_count_k(const int* __restrict__ col, unsigned int* deg, int E) {
    int e = blockIdx.x * blockDim.x + threadIdx.x;
    if (e < E) atomicAdd(&deg[col[e]], 1u);
}

// ---------------- dinv + scan-free CSR segment allocation ----------------

__global__ void alloc_k(const unsigned int* __restrict__ deg, float* __restrict__ dinv,
                        unsigned int* __restrict__ cur, unsigned int* cursor, int n) {
    int i = blockIdx.x * blockDim.x + threadIdx.x;
    int lane = threadIdx.x & 63;
    unsigned int dg = (i < n) ? deg[i] : 1u;
    if (i < n) dinv[i] = rsqrtf((float)dg);  // dg >= 1 (self-loop)
    unsigned int cnt = (i < n) ? (dg - 1u) : 0u;  // in-edges only
    unsigned int v = cnt;  // inclusive wave scan
#pragma unroll
    for (int off = 1; off < 64; off <<= 1) {
        unsigned int t = (unsigned int)__shfl_up((int)v, off, 64);
        if (lane >= off) v += t;
    }
    unsigned int base = 0;
    if (lane == 63) base = atomicAdd(cursor, v);
    base = (unsigned int)__shfl((int)base, 63, 64);
    if (i < n) cur[i] = base + v - cnt;  // segment start; bucket advances to end
}

// ---------------- bucket edges into CSR (src + precomputed weight) ----------------

__global__ void bucket_k(const int* __restrict__ row, const int* __restrict__ col,
                         const float* __restrict__ dinv, unsigned int* __restrict__ cur,
                         int* __restrict__ csr_src, float* __restrict__ csr_w, int E) {
    int e = blockIdx.x * blockDim.x + threadIdx.x;
    if (e >= E) return;
    int j = row[e], i = col[e];
    unsigned int pos = atomicAdd(&cur[i], 1u);
    csr_src[pos] = j;
    csr_w[pos] = dinv[j] * dinv[i];
}

// ---------------- hop: wave = node, 4 edge slots x float4(16 lanes) ----------------
// 4 independent 256B row-gathers in flight per loop iteration (vs 1 in the
// one-edge-per-iter formulation) -> 4x memory-level parallelism vs the latency wall.

__global__ __launch_bounds__(256) void hop4_k(const float* __restrict__ h_in,
                                              const float* __restrict__ dinv,
                                              const unsigned int* __restrict__ deg,
                                              const unsigned int* __restrict__ cur,
                                              const int* __restrict__ csr_src,
                                              const float* __restrict__ csr_w,
                                              float* __restrict__ h_out, int n) {
    int w = threadIdx.x >> 6, lane = threadIdx.x & 63;
    int i = blockIdx.x * 4 + w;
    if (i >= n) return;
    int es = lane >> 4;            // edge slot 0..3
    int f4 = (lane & 15) << 2;     // feature base (float4)
    unsigned int end = cur[i];
    unsigned int cnt = deg[i] - 1u;
    float4 acc = make_float4(0.f, 0.f, 0.f, 0.f);
    for (unsigned int e = end - cnt + es; e < end; e += 4) {
        int j = csr_src[e];
        float wgt = csr_w[e];
        const float4 v = *(const float4*)(h_in + (size_t)j * D + f4);
        acc.x = fmaf(wgt, v.x, acc.x);
        acc.y = fmaf(wgt, v.y, acc.y);
        acc.z = fmaf(wgt, v.z, acc.z);
        acc.w = fmaf(wgt, v.w, acc.w);
    }
    // reduce over the 4 edge slots: xor lane bits 4,5
#pragma unroll
    for (int off = 16; off < 64; off <<= 1) {
        acc.x += __shfl_xor(acc.x, off, 64);
        acc.y += __shfl_xor(acc.y, off, 64);
        acc.z += __shfl_xor(acc.z, off, 64);
        acc.w += __shfl_xor(acc.w, off, 64);
    }
    if (es == 0) {
        float di = dinv[i];
        const float4 s = *(const float4*)(h_in + (size_t)i * D + f4);
        acc.x = fmaf(di * di, s.x, acc.x);
        acc.y = fmaf(di * di, s.y, acc.y);
        acc.z = fmaf(di * di, s.z, acc.z);
        acc.w = fmaf(di * di, s.w, acc.w);
        *(float4*)(h_out + (size_t)i * D + f4) = acc;
    }
}

// ---------------- hop 2 fused with Linear + bias + ReLU ----------------

__global__ __launch_bounds__(256) void hop4_linear_k(const float* __restrict__ h_in,
                                                     const float* __restrict__ dinv,
                                                     const unsigned int* __restrict__ deg,
                                                     const unsigned int* __restrict__ cur,
                                                     const int* __restrict__ csr_src,
                                                     const float* __restrict__ csr_w,
                                                     const float* __restrict__ W,
                                                     const float* __restrict__ b,
                                                     float* __restrict__ out, int n) {
    __shared__ float Wt[D][D + 1];  // Wt[d][o] = W[o][d]; +1 pad -> conflict-free both ways
    __shared__ float sh[4][D];      // per-wave aggregated feature row
    int tid = threadIdx.x;
    for (int k = tid; k < D * D; k += 256) Wt[k & 63][k >> 6] = W[k];
    __syncthreads();
    int w = tid >> 6, lane = tid & 63;
    int i = blockIdx.x * 4 + w;
    if (i >= n) return;
    int es = lane >> 4;
    int f4 = (lane & 15) << 2;
    unsigned int end = cur[i];
    unsigned int cnt = deg[i] - 1u;
    float4 acc = make_float4(0.f, 0.f, 0.f, 0.f);
    for (unsigned int e = end - cnt + es; e < end; e += 4) {
        int j = csr_src[e];
        float wgt = csr_w[e];
        const float4 v = *(const float4*)(h_in + (size_t)j * D + f4);
        acc.x = fmaf(wgt, v.x, acc.x);
        acc.y = fmaf(wgt, v.y, acc.y);
        acc.z = fmaf(wgt, v.z, acc.z);
        acc.w = fmaf(wgt, v.w, acc.w);
    }
#pragma unroll
    for (int off = 16; off < 64; off <<= 1) {
        acc.x += __shfl_xor(acc.x, off, 64);
        acc.y += __shfl_xor(acc.y, off, 64);
        acc.z += __shfl_xor(acc.z, off, 64);
        acc.w += __shfl_xor(acc.w, off, 64);
    }
    if (es == 0) {
        float di = dinv[i];
        const float4 s = *(const float4*)(h_in + (size_t)i * D + f4);
        acc.x = fmaf(di * di, s.x, acc.x);
        acc.y = fmaf(di * di, s.y, acc.y);
        acc.z = fmaf(di * di, s.z, acc.z);
        acc.w = fmaf(di * di, s.w, acc.w);
        *(float4*)&sh[w][f4] = acc;  // same-wave LDS RAW; compiler inserts lgkmcnt
    }
    float o = b[lane];
#pragma unroll
    for (int d = 0; d < D; ++d) o = fmaf(sh[w][d], Wt[d][lane], o);
    out[(size_t)i * D + lane] = fmaxf(o, 0.0f);
}

// ---------------- launch ----------------

extern "C" void kernel_launch(void* const* d_in, const int* in_sizes, int n_in,
                              void* d_out, int out_size, void* d_ws, size_t ws_size,
                              hipStream_t stream) {
    const float* x = (const float*)d_in[0];  // [n, 64]
    const float* W = (const float*)d_in[1];  // [64, 64]
    const float* b = (const float*)d_in[2];  // [64]
    const int*   ei = (const int*)d_in[3];   // [2, E] int32

    const int n = in_sizes[0] / D;
    const int E = in_sizes[3] / 2;
    const int* row = ei;       // sources j
    const int* col = ei + E;   // targets i
    float* out = (float*)d_out;

    // ws (~39.6 MB): deg | dinv | cur | cursor | csr_src | csr_w | h1
    char* ws = (char*)d_ws;
    unsigned int* deg     = (unsigned int*)ws;                        // n u32
    float*        dinv    = (float*)(ws + (size_t)n * 4);             // n f32
    unsigned int* cur     = (unsigned int*)(ws + (size_t)n * 8);      // n u32
    unsigned int* cursor  = (unsigned int*)(ws + (size_t)n * 12);     // 1 u32 (+pad)
    int*          csr_src = (int*)(ws + (size_t)n * 12 + 16);         // E i32
    float*        csr_w   = (float*)(ws + (size_t)n * 12 + 16 + (size_t)E * 4);  // E f32
    float*        h1      = (float*)(ws + (size_t)n * 12 + 16 + (size_t)E * 8);  // n*64 f32

    const int nb = (n + 255) / 256;
    const int eb = (E + 255) / 256;
    const int gb = (n + 3) / 4;

    deg_init_k<<<nb, 256, 0, stream>>>(deg, cursor, n);
    deg_count_k<<<eb, 256, 0, stream>>>(col, deg, E);
    alloc_k<<<nb, 256, 0, stream>>>(deg, dinv, cur, cursor, n);
    bucket_k<<<eb, 256, 0, stream>>>(row, col, dinv, cur, csr_src, csr_w, E);

    hop4_k<<<gb, 256, 0, stream>>>(x, dinv, deg, cur, csr_src, csr_w, h1, n);
    hop4_linear_k<<<gb, 256, 0, stream>>>(h1, dinv, deg, cur, csr_src, csr_w, W, b, out, n);
}

// Round 5
// 423.763 us; speedup vs baseline: 2.3062x; 1.1135x over previous
//
#include <hip/hip_runtime.h>

#define D 64

// ---------------- degree ----------------

__global__ void deg_init_k(unsigned int* deg, unsigned int* cursor, int n) {
    int i = blockIdx.x * blockDim.x + threadIdx.x;
    if (i < n) deg[i] = 1u;  // self-loop
    if (i == 0) *cursor = 0u;
}

__global__ void deg_count_k(const int* __restrict__ col, unsigned int* deg, int E) {
    int e = blockIdx.x * blockDim.x + threadIdx.x;
    if (e < E) atomicAdd(&deg[col[e]], 1u);
}

// ---------------- dinv + scan-free CSR segment allocation ----------------

__global__ void alloc_k(const unsigned int* __restrict__ deg, float* __restrict__ dinv,
                        unsigned int* __restrict__ cur, unsigned int* cursor, int n) {
    int i = blockIdx.x * blockDim.x + threadIdx.x;
    int lane = threadIdx.x & 63;
    unsigned int dg = (i < n) ? deg[i] : 1u;
    if (i < n) dinv[i] = rsqrtf((float)dg);  // dg >= 1 (self-loop)
    unsigned int cnt = (i < n) ? (dg - 1u) : 0u;  // in-edges only
    unsigned int v = cnt;  // inclusive wave scan
#pragma unroll
    for (int off = 1; off < 64; off <<= 1) {
        unsigned int t = (unsigned int)__shfl_up((int)v, off, 64);
        if (lane >= off) v += t;
    }
    unsigned int base = 0;
    if (lane == 63) base = atomicAdd(cursor, v);
    base = (unsigned int)__shfl((int)base, 63, 64);
    if (i < n) cur[i] = base + v - cnt;  // segment start; bucket advances to end
}

// ---------------- bucket edges into packed CSR: one 8B store per edge ----------------

__global__ void bucket_k(const int* __restrict__ row, const int* __restrict__ col,
                         const float* __restrict__ dinv, unsigned int* __restrict__ cur,
                         int2* __restrict__ csr, int E) {
    int e = blockIdx.x * blockDim.x + threadIdx.x;
    if (e >= E) return;
    int j = row[e], i = col[e];
    unsigned int pos = atomicAdd(&cur[i], 1u);
    csr[pos] = make_int2(j, __float_as_int(dinv[j] * dinv[i]));
}

// ---------------- hop: wave = node, 4 edge slots x float4(16 lanes), unroll 2 --------
// 8 independent 256B row-gathers in flight per wave per iteration.

__global__ __launch_bounds__(256) void hop4_k(const float* __restrict__ h_in,
                                              const float* __restrict__ dinv,
                                              const unsigned int* __restrict__ deg,
                                              const unsigned int* __restrict__ cur,
                                              const int2* __restrict__ csr,
                                              float* __restrict__ h_out, int n) {
    int w = threadIdx.x >> 6, lane = threadIdx.x & 63;
    int i = blockIdx.x * 4 + w;
    if (i >= n) return;
    int es = lane >> 4;            // edge slot 0..3
    int f4 = (lane & 15) << 2;     // feature base (float4)
    unsigned int end = cur[i];
    unsigned int cnt = deg[i] - 1u;
    float4 a0 = make_float4(0.f, 0.f, 0.f, 0.f);
    float4 a1 = make_float4(0.f, 0.f, 0.f, 0.f);
    unsigned int e = end - cnt + es;
    for (; e + 4 < end; e += 8) {  // two independent gather chains
        int2 p0 = csr[e];
        int2 p1 = csr[e + 4];
        float w0 = __int_as_float(p0.y), w1 = __int_as_float(p1.y);
        const float4 v0 = *(const float4*)(h_in + (size_t)p0.x * D + f4);
        const float4 v1 = *(const float4*)(h_in + (size_t)p1.x * D + f4);
        a0.x = fmaf(w0, v0.x, a0.x); a0.y = fmaf(w0, v0.y, a0.y);
        a0.z = fmaf(w0, v0.z, a0.z); a0.w = fmaf(w0, v0.w, a0.w);
        a1.x = fmaf(w1, v1.x, a1.x); a1.y = fmaf(w1, v1.y, a1.y);
        a1.z = fmaf(w1, v1.z, a1.z); a1.w = fmaf(w1, v1.w, a1.w);
    }
    if (e < end) {  // per-slot tail (at most one)
        int2 p = csr[e];
        float wt = __int_as_float(p.y);
        const float4 v = *(const float4*)(h_in + (size_t)p.x * D + f4);
        a0.x = fmaf(wt, v.x, a0.x); a0.y = fmaf(wt, v.y, a0.y);
        a0.z = fmaf(wt, v.z, a0.z); a0.w = fmaf(wt, v.w, a0.w);
    }
    float4 acc = make_float4(a0.x + a1.x, a0.y + a1.y, a0.z + a1.z, a0.w + a1.w);
#pragma unroll
    for (int off = 16; off < 64; off <<= 1) {  // reduce over 4 edge slots
        acc.x += __shfl_xor(acc.x, off, 64);
        acc.y += __shfl_xor(acc.y, off, 64);
        acc.z += __shfl_xor(acc.z, off, 64);
        acc.w += __shfl_xor(acc.w, off, 64);
    }
    if (es == 0) {
        float di = dinv[i];
        const float4 s = *(const float4*)(h_in + (size_t)i * D + f4);
        acc.x = fmaf(di * di, s.x, acc.x);
        acc.y = fmaf(di * di, s.y, acc.y);
        acc.z = fmaf(di * di, s.z, acc.z);
        acc.w = fmaf(di * di, s.w, acc.w);
        *(float4*)(h_out + (size_t)i * D + f4) = acc;
    }
}

// ---------------- hop 2 fused with Linear + bias + ReLU ----------------

__global__ __launch_bounds__(256) void hop4_linear_k(const float* __restrict__ h_in,
                                                     const float* __restrict__ dinv,
                                                     const unsigned int* __restrict__ deg,
                                                     const unsigned int* __restrict__ cur,
                                                     const int2* __restrict__ csr,
                                                     const float* __restrict__ W,
                                                     const float* __restrict__ b,
                                                     float* __restrict__ out, int n) {
    __shared__ float Wt[D][D + 1];  // Wt[d][o] = W[o][d]; +1 pad -> conflict-free
    __shared__ float sh[4][D];      // per-wave aggregated feature row
    int tid = threadIdx.x;
    for (int k = tid; k < D * D; k += 256) Wt[k & 63][k >> 6] = W[k];
    __syncthreads();
    int w = tid >> 6, lane = tid & 63;
    int i = blockIdx.x * 4 + w;
    if (i >= n) return;
    int es = lane >> 4;
    int f4 = (lane & 15) << 2;
    unsigned int end = cur[i];
    unsigned int cnt = deg[i] - 1u;
    float4 a0 = make_float4(0.f, 0.f, 0.f, 0.f);
    float4 a1 = make_float4(0.f, 0.f, 0.f, 0.f);
    unsigned int e = end - cnt + es;
    for (; e + 4 < end; e += 8) {
        int2 p0 = csr[e];
        int2 p1 = csr[e + 4];
        float w0 = __int_as_float(p0.y), w1 = __int_as_float(p1.y);
        const float4 v0 = *(const float4*)(h_in + (size_t)p0.x * D + f4);
        const float4 v1 = *(const float4*)(h_in + (size_t)p1.x * D + f4);
        a0.x = fmaf(w0, v0.x, a0.x); a0.y = fmaf(w0, v0.y, a0.y);
        a0.z = fmaf(w0, v0.z, a0.z); a0.w = fmaf(w0, v0.w, a0.w);
        a1.x = fmaf(w1, v1.x, a1.x); a1.y = fmaf(w1, v1.y, a1.y);
        a1.z = fmaf(w1, v1.z, a1.z); a1.w = fmaf(w1, v1.w, a1.w);
    }
    if (e < end) {
        int2 p = csr[e];
        float wt = __int_as_float(p.y);
        const float4 v = *(const float4*)(h_in + (size_t)p.x * D + f4);
        a0.x = fmaf(wt, v.x, a0.x); a0.y = fmaf(wt, v.y, a0.y);
        a0.z = fmaf(wt, v.z, a0.z); a0.w = fmaf(wt, v.w, a0.w);
    }
    float4 acc = make_float4(a0.x + a1.x, a0.y + a1.y, a0.z + a1.z, a0.w + a1.w);
#pragma unroll
    for (int off = 16; off < 64; off <<= 1) {
        acc.x += __shfl_xor(acc.x, off, 64);
        acc.y += __shfl_xor(acc.y, off, 64);
        acc.z += __shfl_xor(acc.z, off, 64);
        acc.w += __shfl_xor(acc.w, off, 64);
    }
    if (es == 0) {
        float di = dinv[i];
        const float4 s = *(const float4*)(h_in + (size_t)i * D + f4);
        acc.x = fmaf(di * di, s.x, acc.x);
        acc.y = fmaf(di * di, s.y, acc.y);
        acc.z = fmaf(di * di, s.z, acc.z);
        acc.w = fmaf(di * di, s.w, acc.w);
        *(float4*)&sh[w][f4] = acc;  // same-wave LDS RAW; compiler inserts lgkmcnt
    }
    float o = b[lane];
#pragma unroll
    for (int d = 0; d < D; ++d) o = fmaf(sh[w][d], Wt[d][lane], o);
    out[(size_t)i * D + lane] = fmaxf(o, 0.0f);
}

// ---------------- launch ----------------

extern "C" void kernel_launch(void* const* d_in, const int* in_sizes, int n_in,
                              void* d_out, int out_size, void* d_ws, size_t ws_size,
                              hipStream_t stream) {
    const float* x = (const float*)d_in[0];  // [n, 64]
    const float* W = (const float*)d_in[1];  // [64, 64]
    const float* b = (const float*)d_in[2];  // [64]
    const int*   ei = (const int*)d_in[3];   // [2, E] int32

    const int n = in_sizes[0] / D;
    const int E = in_sizes[3] / 2;
    const int* row = ei;       // sources j
    const int* col = ei + E;   // targets i
    float* out = (float*)d_out;

    // ws (~39.6 MB): deg | dinv | cur | cursor | csr(int2) | h1
    char* ws = (char*)d_ws;
    unsigned int* deg     = (unsigned int*)ws;                        // n u32
    float*        dinv    = (float*)(ws + (size_t)n * 4);             // n f32
    unsigned int* cur     = (unsigned int*)(ws + (size_t)n * 8);      // n u32
    unsigned int* cursor  = (unsigned int*)(ws + (size_t)n * 12);     // 1 u32 (+pad)
    int2*         csr     = (int2*)(ws + (size_t)n * 12 + 16);        // E int2
    float*        h1      = (float*)(ws + (size_t)n * 12 + 16 + (size_t)E * 8);  // n*64 f32

    const int nb = (n + 255) / 256;
    const int eb = (E + 255) / 256;
    const int gb = (n + 3) / 4;

    deg_init_k<<<nb, 256, 0, stream>>>(deg, cursor, n);
    deg_count_k<<<eb, 256, 0, stream>>>(col, deg, E);
    alloc_k<<<nb, 256, 0, stream>>>(deg, dinv, cur, cursor, n);
    bucket_k<<<eb, 256, 0, stream>>>(row, col, dinv, cur, csr, E);

    hop4_k<<<gb, 256, 0, stream>>>(x, dinv, deg, cur, csr, h1, n);
    hop4_linear_k<<<gb, 256, 0, stream>>>(h1, dinv, deg, cur, csr, W, b, out, n);
}

// Round 6
// 415.391 us; speedup vs baseline: 2.3527x; 1.0202x over previous
//
#include <hip/hip_runtime.h>
#include <hip/hip_fp16.h>

#define D 64

// ---------------- degree ----------------

__global__ void deg_init_k(unsigned int* deg, unsigned int* cursor, int n) {
    int i = blockIdx.x * blockDim.x + threadIdx.x;
    if (i < n) deg[i] = 1u;  // self-loop
    if (i == 0) *cursor = 0u;
}

__global__ void deg_count_k(const int* __restrict__ col, unsigned int* deg, int E) {
    int e = blockIdx.x * blockDim.x + threadIdx.x;
    if (e < E) atomicAdd(&deg[col[e]], 1u);
}

// ---------------- dinv + scan-free CSR segment allocation ----------------

__global__ void alloc_k(const unsigned int* __restrict__ deg, float* __restrict__ dinv,
                        unsigned int* __restrict__ cur, unsigned int* cursor, int n) {
    int i = blockIdx.x * blockDim.x + threadIdx.x;
    int lane = threadIdx.x & 63;
    unsigned int dg = (i < n) ? deg[i] : 1u;
    if (i < n) dinv[i] = rsqrtf((float)dg);  // dg >= 1 (self-loop)
    unsigned int cnt = (i < n) ? (dg - 1u) : 0u;  // in-edges only
    unsigned int v = cnt;  // inclusive wave scan
#pragma unroll
    for (int off = 1; off < 64; off <<= 1) {
        unsigned int t = (unsigned int)__shfl_up((int)v, off, 64);
        if (lane >= off) v += t;
    }
    unsigned int base = 0;
    if (lane == 63) base = atomicAdd(cursor, v);
    base = (unsigned int)__shfl((int)base, 63, 64);
    if (i < n) cur[i] = base + v - cnt;  // segment start; bucket advances to end
}

// ---------------- bucket edges into packed CSR: one 8B store per edge ----------------

__global__ void bucket_k(const int* __restrict__ row, const int* __restrict__ col,
                         const float* __restrict__ dinv, unsigned int* __restrict__ cur,
                         int2* __restrict__ csr, int E) {
    int e = blockIdx.x * blockDim.x + threadIdx.x;
    if (e >= E) return;
    int j = row[e], i = col[e];
    unsigned int pos = atomicAdd(&cur[i], 1u);
    csr[pos] = make_int2(j, __float_as_int(dinv[j] * dinv[i]));
}

// ---------------- fp32 -> fp16 feature conversion ----------------

__global__ void f2h_k(const float* __restrict__ x, __half* __restrict__ xh, int n16) {
    int t = blockIdx.x * blockDim.x + threadIdx.x;  // n*16 threads, 4 floats each
    if (t >= n16) return;
    float4 v = ((const float4*)x)[t];
    __half2* o = (__half2*)(xh + (size_t)t * 4);
    o[0] = __float22half2_rn(make_float2(v.x, v.y));
    o[1] = __float22half2_rn(make_float2(v.z, v.w));
}

// ---------------- helpers ----------------

__device__ __forceinline__ void fma_row8(float acc[8], float wgt, float4 raw) {
    const __half2* q = (const __half2*)&raw;
#pragma unroll
    for (int k = 0; k < 4; ++k) {
        float2 f = __half22float2(q[k]);
        acc[2 * k]     = fmaf(wgt, f.x, acc[2 * k]);
        acc[2 * k + 1] = fmaf(wgt, f.y, acc[2 * k + 1]);
    }
}

// ---------------- hop: wave = node, 8 edge slots x 8 lanes x 16B(8 halves) ----------
// 8 slots x unroll 2 = 16 independent 128B row-gathers in flight per wave.

__global__ __launch_bounds__(256) void hop8_k(const __half* __restrict__ h_in,
                                              const float* __restrict__ dinv,
                                              const unsigned int* __restrict__ deg,
                                              const unsigned int* __restrict__ cur,
                                              const int2* __restrict__ csr,
                                              __half* __restrict__ h_out, int n) {
    int w = threadIdx.x >> 6, lane = threadIdx.x & 63;
    int i = blockIdx.x * 4 + w;
    if (i >= n) return;
    int es = lane >> 3;          // edge slot 0..7
    int fb = (lane & 7) << 3;    // feature base (8 halves = 16B)
    unsigned int end = cur[i];
    unsigned int cnt = deg[i] - 1u;
    float a0[8] = {0, 0, 0, 0, 0, 0, 0, 0};
    float a1[8] = {0, 0, 0, 0, 0, 0, 0, 0};
    unsigned int e = end - cnt + es;
    for (; e + 8 < end; e += 16) {  // two independent gather chains
        int2 p0 = csr[e];
        int2 p1 = csr[e + 8];
        float4 r0 = *(const float4*)(h_in + (size_t)p0.x * D + fb);
        float4 r1 = *(const float4*)(h_in + (size_t)p1.x * D + fb);
        fma_row8(a0, __int_as_float(p0.y), r0);
        fma_row8(a1, __int_as_float(p1.y), r1);
    }
    if (e < end) {  // per-slot tail (at most one)
        int2 p = csr[e];
        float4 r = *(const float4*)(h_in + (size_t)p.x * D + fb);
        fma_row8(a0, __int_as_float(p.y), r);
    }
    float acc[8];
#pragma unroll
    for (int k = 0; k < 8; ++k) acc[k] = a0[k] + a1[k];
#pragma unroll
    for (int off = 8; off < 64; off <<= 1) {  // reduce over 8 edge slots
#pragma unroll
        for (int k = 0; k < 8; ++k) acc[k] += __shfl_xor(acc[k], off, 64);
    }
    if (es == 0) {
        float di = dinv[i];
        float4 s = *(const float4*)(h_in + (size_t)i * D + fb);
        fma_row8(acc, di * di, s);  // self-loop term
        float4 outv;
        __half2* o = (__half2*)&outv;
        o[0] = __float22half2_rn(make_float2(acc[0], acc[1]));
        o[1] = __float22half2_rn(make_float2(acc[2], acc[3]));
        o[2] = __float22half2_rn(make_float2(acc[4], acc[5]));
        o[3] = __float22half2_rn(make_float2(acc[6], acc[7]));
        *(float4*)(h_out + (size_t)i * D + fb) = outv;
    }
}

// ---------------- hop 2 fused with Linear + bias + ReLU (fp32 math) ----------------

__global__ __launch_bounds__(256) void hop8_linear_k(const __half* __restrict__ h_in,
                                                     const float* __restrict__ dinv,
                                                     const unsigned int* __restrict__ deg,
                                                     const unsigned int* __restrict__ cur,
                                                     const int2* __restrict__ csr,
                                                     const float* __restrict__ W,
                                                     const float* __restrict__ b,
                                                     float* __restrict__ out, int n) {
    __shared__ float Wt[D][D + 1];  // Wt[d][o] = W[o][d]; +1 pad -> conflict-free
    __shared__ float sh[4][D];      // per-wave aggregated feature row (fp32)
    int tid = threadIdx.x;
    for (int k = tid; k < D * D; k += 256) Wt[k & 63][k >> 6] = W[k];
    __syncthreads();
    int w = tid >> 6, lane = tid & 63;
    int i = blockIdx.x * 4 + w;
    if (i >= n) return;
    int es = lane >> 3;
    int fb = (lane & 7) << 3;
    unsigned int end = cur[i];
    unsigned int cnt = deg[i] - 1u;
    float a0[8] = {0, 0, 0, 0, 0, 0, 0, 0};
    float a1[8] = {0, 0, 0, 0, 0, 0, 0, 0};
    unsigned int e = end - cnt + es;
    for (; e + 8 < end; e += 16) {
        int2 p0 = csr[e];
        int2 p1 = csr[e + 8];
        float4 r0 = *(const float4*)(h_in + (size_t)p0.x * D + fb);
        float4 r1 = *(const float4*)(h_in + (size_t)p1.x * D + fb);
        fma_row8(a0, __int_as_float(p0.y), r0);
        fma_row8(a1, __int_as_float(p1.y), r1);
    }
    if (e < end) {
        int2 p = csr[e];
        float4 r = *(const float4*)(h_in + (size_t)p.x * D + fb);
        fma_row8(a0, __int_as_float(p.y), r);
    }
    float acc[8];
#pragma unroll
    for (int k = 0; k < 8; ++k) acc[k] = a0[k] + a1[k];
#pragma unroll
    for (int off = 8; off < 64; off <<= 1) {
#pragma unroll
        for (int k = 0; k < 8; ++k) acc[k] += __shfl_xor(acc[k], off, 64);
    }
    if (es == 0) {
        float di = dinv[i];
        float4 s = *(const float4*)(h_in + (size_t)i * D + fb);
        fma_row8(acc, di * di, s);
        *(float4*)&sh[w][fb]     = make_float4(acc[0], acc[1], acc[2], acc[3]);
        *(float4*)&sh[w][fb + 4] = make_float4(acc[4], acc[5], acc[6], acc[7]);
    }
    // same-wave LDS RAW (lanes 0..7 wrote wave-private row); compiler inserts lgkmcnt
    float o = b[lane];
#pragma unroll
    for (int d = 0; d < D; ++d) o = fmaf(sh[w][d], Wt[d][lane], o);
    out[(size_t)i * D + lane] = fmaxf(o, 0.0f);
}

// ---------------- launch ----------------

extern "C" void kernel_launch(void* const* d_in, const int* in_sizes, int n_in,
                              void* d_out, int out_size, void* d_ws, size_t ws_size,
                              hipStream_t stream) {
    const float* x = (const float*)d_in[0];  // [n, 64]
    const float* W = (const float*)d_in[1];  // [64, 64]
    const float* b = (const float*)d_in[2];  // [64]
    const int*   ei = (const int*)d_in[3];   // [2, E] int32

    const int n = in_sizes[0] / D;
    const int E = in_sizes[3] / 2;
    const int* row = ei;       // sources j
    const int* col = ei + E;   // targets i
    float* out = (float*)d_out;

    // ws (~40 MB): deg | dinv | cur | cursor | csr(int2) | xh(half) | h1h(half)
    char* ws = (char*)d_ws;
    unsigned int* deg     = (unsigned int*)ws;                        // n u32
    float*        dinv    = (float*)(ws + (size_t)n * 4);             // n f32
    unsigned int* cur     = (unsigned int*)(ws + (size_t)n * 8);      // n u32
    unsigned int* cursor  = (unsigned int*)(ws + (size_t)n * 12);     // 1 u32 (+pad)
    int2*         csr     = (int2*)(ws + (size_t)n * 12 + 16);        // E int2
    __half*       xh      = (__half*)(ws + (size_t)n * 12 + 16 + (size_t)E * 8);      // n*64 half
    __half*       h1h     = (__half*)(ws + (size_t)n * 12 + 16 + (size_t)E * 8
                                      + (size_t)n * D * 2);                           // n*64 half

    const int nb = (n + 255) / 256;
    const int eb = (E + 255) / 256;
    const int gb = (n + 3) / 4;
    const int cb = (n * 16 + 255) / 256;

    deg_init_k<<<nb, 256, 0, stream>>>(deg, cursor, n);
    deg_count_k<<<eb, 256, 0, stream>>>(col, deg, E);
    alloc_k<<<nb, 256, 0, stream>>>(deg, dinv, cur, cursor, n);
    bucket_k<<<eb, 256, 0, stream>>>(row, col, dinv, cur, csr, E);
    f2h_k<<<cb, 256, 0, stream>>>(x, xh, n * 16);

    hop8_k<<<gb, 256, 0, stream>>>(xh, dinv, deg, cur, csr, h1h, n);
    hop8_linear_k<<<gb, 256, 0, stream>>>(h1h, dinv, deg, cur, csr, W, b, out, n);
}

// Round 7
// 408.465 us; speedup vs baseline: 2.3926x; 1.0170x over previous
//
#include <hip/hip_runtime.h>
#include <hip/hip_fp16.h>

#define D 64

// ---------------- degree ----------------

__global__ void deg_init_k(unsigned int* deg, unsigned int* cursor, int n) {
    int i = blockIdx.x * blockDim.x + threadIdx.x;
    if (i < n) deg[i] = 1u;  // self-loop
    if (i == 0) *cursor = 0u;
}

__global__ void deg_count_k(const int* __restrict__ col, unsigned int* deg, int E) {
    int e = blockIdx.x * blockDim.x + threadIdx.x;
    if (e < E) atomicAdd(&deg[col[e]], 1u);
}

// ---------------- dinv + scan-free CSR segment allocation ----------------
// Emits packed seg[i] = {start, cnt} so hops do ONE 8B load per node (shallower
// serial prologue chain), plus working cursor cur[i] for the bucket pass.

__global__ void alloc_k(const unsigned int* __restrict__ deg, float* __restrict__ dinv,
                        uint2* __restrict__ seg, unsigned int* __restrict__ cur,
                        unsigned int* cursor, int n) {
    int i = blockIdx.x * blockDim.x + threadIdx.x;
    int lane = threadIdx.x & 63;
    unsigned int dg = (i < n) ? deg[i] : 1u;
    if (i < n) dinv[i] = rsqrtf((float)dg);  // dg >= 1 (self-loop)
    unsigned int cnt = (i < n) ? (dg - 1u) : 0u;  // in-edges only
    unsigned int v = cnt;  // inclusive wave scan
#pragma unroll
    for (int off = 1; off < 64; off <<= 1) {
        unsigned int t = (unsigned int)__shfl_up((int)v, off, 64);
        if (lane >= off) v += t;
    }
    unsigned int base = 0;
    if (lane == 63) base = atomicAdd(cursor, v);
    base = (unsigned int)__shfl((int)base, 63, 64);
    if (i < n) {
        unsigned int start = base + v - cnt;
        seg[i] = make_uint2(start, cnt);
        cur[i] = start;
    }
}

// ---------------- bucket edges into packed CSR: one 8B store per edge ----------------

__global__ void bucket_k(const int* __restrict__ row, const int* __restrict__ col,
                         const float* __restrict__ dinv, unsigned int* __restrict__ cur,
                         int2* __restrict__ csr, int E) {
    int e = blockIdx.x * blockDim.x + threadIdx.x;
    if (e >= E) return;
    int j = row[e], i = col[e];
    unsigned int pos = atomicAdd(&cur[i], 1u);
    csr[pos] = make_int2(j, __float_as_int(dinv[j] * dinv[i]));
}

// ---------------- fp32 -> fp16 feature conversion ----------------

__global__ void f2h_k(const float* __restrict__ x, __half* __restrict__ xh, int n16) {
    int t = blockIdx.x * blockDim.x + threadIdx.x;  // n*16 threads, 4 floats each
    if (t >= n16) return;
    float4 v = ((const float4*)x)[t];
    __half2* o = (__half2*)(xh + (size_t)t * 4);
    o[0] = __float22half2_rn(make_float2(v.x, v.y));
    o[1] = __float22half2_rn(make_float2(v.z, v.w));
}

// ---------------- helpers ----------------

__device__ __forceinline__ void fma_row8(float acc[8], float wgt, float4 raw) {
    const __half2* q = (const __half2*)&raw;
#pragma unroll
    for (int k = 0; k < 4; ++k) {
        float2 f = __half22float2(q[k]);
        acc[2 * k]     = fmaf(wgt, f.x, acc[2 * k]);
        acc[2 * k + 1] = fmaf(wgt, f.y, acc[2 * k + 1]);
    }
}

// Per-slot edge aggregation: 8-lane group owns node i, iterates its own edges.
// Unroll 2 (dup-load predicated tail) -> up to 16 independent row gathers/wave,
// sustained for the whole wave lifetime. No cross-slot reduction needed.
__device__ __forceinline__ void aggregate_node(const __half* __restrict__ h_in,
                                               const int2* __restrict__ csr,
                                               uint2 sg, int fb, float acc[8]) {
#pragma unroll
    for (int k = 0; k < 8; ++k) acc[k] = 0.0f;
    float a1[8] = {0, 0, 0, 0, 0, 0, 0, 0};
    unsigned int e = sg.x, end = sg.x + sg.y;
    for (; e < end; e += 2) {
        int2 p0 = csr[e];
        bool has1 = (e + 1u < end);
        int2 p1 = csr[has1 ? e + 1u : e];  // dup load on tail (cache hit, predication-free addr)
        float4 r0 = *(const float4*)(h_in + (size_t)p0.x * D + fb);
        float4 r1 = *(const float4*)(h_in + (size_t)p1.x * D + fb);
        fma_row8(acc, __int_as_float(p0.y), r0);
        if (has1) fma_row8(a1, __int_as_float(p1.y), r1);
    }
#pragma unroll
    for (int k = 0; k < 8; ++k) acc[k] += a1[k];
}

// ---------------- hop 1: wave = 8 nodes, 8 lanes per node ----------------

__global__ __launch_bounds__(256) void hop8s_k(const __half* __restrict__ h_in,
                                               const float* __restrict__ dinv,
                                               const uint2* __restrict__ seg,
                                               const int2* __restrict__ csr,
                                               __half* __restrict__ h_out, int n) {
    int wave = blockIdx.x * 4 + (threadIdx.x >> 6);
    int lane = threadIdx.x & 63;
    int g = lane >> 3;          // node slot 0..7
    int fb = (lane & 7) << 3;   // feature base (8 halves = 16B)
    int i = wave * 8 + g;
    bool valid = (i < n);
    uint2 sg = valid ? seg[i] : make_uint2(0u, 0u);
    float acc[8];
    aggregate_node(h_in, csr, sg, fb, acc);
    if (valid) {
        float di = dinv[i];
        float4 s = *(const float4*)(h_in + (size_t)i * D + fb);
        fma_row8(acc, di * di, s);  // self-loop term
        float4 outv;
        __half2* o = (__half2*)&outv;
        o[0] = __float22half2_rn(make_float2(acc[0], acc[1]));
        o[1] = __float22half2_rn(make_float2(acc[2], acc[3]));
        o[2] = __float22half2_rn(make_float2(acc[4], acc[5]));
        o[3] = __float22half2_rn(make_float2(acc[6], acc[7]));
        *(float4*)(h_out + (size_t)i * D + fb) = outv;
    }
}

// ---------------- hop 2 fused with Linear + bias + ReLU (fp32 math) ----------------

__global__ __launch_bounds__(256) void hop8s_linear_k(const __half* __restrict__ h_in,
                                                      const float* __restrict__ dinv,
                                                      const uint2* __restrict__ seg,
                                                      const int2* __restrict__ csr,
                                                      const float* __restrict__ W,
                                                      const float* __restrict__ b,
                                                      float* __restrict__ out, int n) {
    __shared__ float Wt[D][D + 1];   // Wt[d][o] = W[o][d]; +1 pad -> conflict-free
    __shared__ float sh[4][8][D];    // per-wave: 8 aggregated node rows (fp32)
    int tid = threadIdx.x;
    for (int k = tid; k < D * D; k += 256) Wt[k & 63][k >> 6] = W[k];
    __syncthreads();
    int w = tid >> 6, lane = tid & 63;
    int wave = blockIdx.x * 4 + w;
    int g = lane >> 3;
    int fb = (lane & 7) << 3;
    int i = wave * 8 + g;
    bool valid = (i < n);
    uint2 sg = valid ? seg[i] : make_uint2(0u, 0u);
    float acc[8];
    aggregate_node(h_in, csr, sg, fb, acc);
    if (valid) {
        float di = dinv[i];
        float4 s = *(const float4*)(h_in + (size_t)i * D + fb);
        fma_row8(acc, di * di, s);
        *(float4*)&sh[w][g][fb]     = make_float4(acc[0], acc[1], acc[2], acc[3]);
        *(float4*)&sh[w][g][fb + 4] = make_float4(acc[4], acc[5], acc[6], acc[7]);
    }
    // readers are the SAME wave -> compiler inserts lgkmcnt wait; no barrier needed
    float bias = b[lane];
#pragma unroll 1
    for (int nd = 0; nd < 8; ++nd) {
        int i2 = wave * 8 + nd;       // wave-uniform
        if (i2 >= n) break;
        float o = bias;
#pragma unroll
        for (int d = 0; d < D; ++d) o = fmaf(sh[w][nd][d], Wt[d][lane], o);
        out[(size_t)i2 * D + lane] = fmaxf(o, 0.0f);
    }
}

// ---------------- launch ----------------

extern "C" void kernel_launch(void* const* d_in, const int* in_sizes, int n_in,
                              void* d_out, int out_size, void* d_ws, size_t ws_size,
                              hipStream_t stream) {
    const float* x = (const float*)d_in[0];  // [n, 64]
    const float* W = (const float*)d_in[1];  // [64, 64]
    const float* b = (const float*)d_in[2];  // [64]
    const int*   ei = (const int*)d_in[3];   // [2, E] int32

    const int n = in_sizes[0] / D;
    const int E = in_sizes[3] / 2;
    const int* row = ei;       // sources j
    const int* col = ei + E;   // targets i
    float* out = (float*)d_out;

    // ws (~41 MB): deg | dinv | cur | seg(uint2) | cursor | csr(int2) | xh | h1h
    char* ws = (char*)d_ws;
    unsigned int* deg     = (unsigned int*)ws;                        // n u32
    float*        dinv    = (float*)(ws + (size_t)n * 4);             // n f32
    unsigned int* cur     = (unsigned int*)(ws + (size_t)n * 8);      // n u32
    uint2*        seg     = (uint2*)(ws + (size_t)n * 12);            // n uint2
    unsigned int* cursor  = (unsigned int*)(ws + (size_t)n * 20);     // 1 u32 (+pad)
    int2*         csr     = (int2*)(ws + (size_t)n * 20 + 16);        // E int2
    __half*       xh      = (__half*)(ws + (size_t)n * 20 + 16 + (size_t)E * 8);  // n*64 half
    __half*       h1h     = (__half*)(ws + (size_t)n * 20 + 16 + (size_t)E * 8
                                      + (size_t)n * D * 2);                        // n*64 half

    const int nb = (n + 255) / 256;
    const int eb = (E + 255) / 256;
    const int gb = (n + 31) / 32;     // wave = 8 nodes, block = 32 nodes
    const int cb = (n * 16 + 255) / 256;

    deg_init_k<<<nb, 256, 0, stream>>>(deg, cursor, n);
    deg_count_k<<<eb, 256, 0, stream>>>(col, deg, E);
    alloc_k<<<nb, 256, 0, stream>>>(deg, dinv, seg, cur, cursor, n);
    bucket_k<<<eb, 256, 0, stream>>>(row, col, dinv, cur, csr, E);
    f2h_k<<<cb, 256, 0, stream>>>(x, xh, n * 16);

    hop8s_k<<<gb, 256, 0, stream>>>(xh, dinv, seg, csr, h1h, n);
    hop8s_linear_k<<<gb, 256, 0, stream>>>(h1h, dinv, seg, csr, W, b, out, n);
}